// Round 2
// baseline (93018.689 us; speedup 1.0000x reference)
//
#include <hip/hip_runtime.h>
#include <cstddef>
#include <cstdint>

#define NODE 207
#define HID 16
#define BATCH 64
#define TSTEPS 12
#define HIDDEN 6624            // NODE*HID*2
#define K_IH 16560             // NODE*HID*5
#define H4 1656                // HIDDEN/4

// ---------------------------------------------------------------------------
// Kernel A: build transposed input inpT (K_IH, 64) for outer step t.
// One block per (b, n). inpT[k*64 + b].  (unchanged from passing version)
// ---------------------------------------------------------------------------
__global__ __launch_bounds__(256) void build_inp_kernel(
    const float* __restrict__ spline,   // (12,64,207,2)
    const float* __restrict__ hz,       // (64,6624)
    const float* __restrict__ Wf,       // (16,32)
    const float* __restrict__ bf,       // (32,)
    const float* __restrict__ Wg,       // (16,256)
    const float* __restrict__ bg,       // (256,)
    const float* __restrict__ conv_w,   // (16,)
    float* __restrict__ inpT,           // (16560,64)
    int t)
{
    const int bn = blockIdx.x;
    const int n = bn % NODE;
    const int b = bn / NODE;
    const int tid = threadIdx.x;

    __shared__ float shz[32];
    __shared__ float sf[32];
    __shared__ float sg[256];

    if (tid < 32) shz[tid] = hz[(size_t)b * HIDDEN + n * 32 + tid];
    __syncthreads();

    {
        float accg = bg[tid];
        #pragma unroll
        for (int i = 0; i < 16; ++i)
            accg = fmaf(shz[2 * i + 1], Wg[i * 256 + tid], accg);
        sg[tid] = tanhf(accg);
    }
    if (tid < 32) {
        float accf = bf[tid];
        #pragma unroll
        for (int i = 0; i < 16; ++i)
            accf = fmaf(shz[2 * i], Wf[i * 32 + tid], accf);
        float fv = tanhf(accf);
        sf[tid] = fv;
        int i2 = tid >> 1, kk = tid & 1;
        int kf = 3312 + n * 64 + i2 * 4 + kk * 2;      // s = 0
        inpT[(size_t)kf * 64 + b] = fv;
    } else if (tid < 48) {
        int i = tid - 32;
        float v = spline[((((size_t)t * BATCH + b) * NODE + n) * 2) + 1];
        inpT[(size_t)(i * NODE + n) * 64 + b] = conv_w[i] * v;
    }
    __syncthreads();
    if (tid < 32) {
        int i2 = tid >> 1, kk = tid & 1;
        float acc = 0.f;
        #pragma unroll
        for (int j = 0; j < 16; ++j)
            acc = fmaf(sg[i2 * 16 + j], sf[j * 2 + kk], acc);
        int kfg = 3312 + n * 64 + i2 * 4 + kk * 2 + 1; // s = 1
        inpT[(size_t)kfg * 64 + b] = acc;
    }
}

// ---------------------------------------------------------------------------
// Kernel B: preK[b][j] = sum_{k in half} inp[b,k] * W_ih[j,k]
// Grid: 414 j-tiles (16 rows) x 2 k-halves = 828 blocks. Block 256 thr.
// LDS-tiled: inp chunk (36 k x 64 b) + W chunk (16 j x 36 k) staged with
// coalesced float4 loads; W read back via LDS broadcast (lane-uniform, free),
// inp read with 2-way-aliased conflict-free b32. No atomics: two partial
// buffers pre0/pre1 summed in the RNN kernel.
// ---------------------------------------------------------------------------
#define KHALF 8280
#define KC 36
#define NCH 230                 // 8280/36

__global__ __launch_bounds__(256) void gemm_ih_kernel(
    const float* __restrict__ Wih,      // (6624,16560)
    const float* __restrict__ inpT,     // (16560,64)
    float* __restrict__ pre0,           // (64,6624)
    float* __restrict__ pre1)           // (64,6624)
{
    const int jt = blockIdx.x >> 1;     // 0..413
    const int kc = blockIdx.x & 1;      // 0..1
    const int j0 = jt * 16;
    const int tid = threadIdx.x;
    const int b = tid & 63;
    const int jg = tid >> 6;            // 0..3 -> j_local = jg*4 + q

    __shared__ __align__(16) float s_inp[KC][64];   // 9 KB
    __shared__ __align__(16) float s_w[16][KC];     // 2.3 KB

    float acc[4] = {0.f, 0.f, 0.f, 0.f};

    const int kbase = kc * KHALF;

    for (int ch = 0; ch < NCH; ++ch) {
        const int kb = kbase + ch * KC;
        __syncthreads();
        // stage inp chunk: 36 rows x 16 float4 = 576 float4
        for (int idx = tid; idx < 576; idx += 256) {
            const int k = idx >> 4;
            const int c = (idx & 15) << 2;
            *reinterpret_cast<float4*>(&s_inp[k][c]) =
                *reinterpret_cast<const float4*>(inpT + (size_t)(kb + k) * 64 + c);
        }
        // stage W chunk: 16 rows x 9 float4 = 144 float4
        if (tid < 144) {
            const int j = tid / 9;
            const int c = (tid % 9) << 2;
            *reinterpret_cast<float4*>(&s_w[j][c]) =
                *reinterpret_cast<const float4*>(Wih + (size_t)(j0 + j) * K_IH + kb + c);
        }
        __syncthreads();

        #pragma unroll
        for (int kq = 0; kq < 9; ++kq) {
            const float a0 = s_inp[kq * 4 + 0][b];
            const float a1 = s_inp[kq * 4 + 1][b];
            const float a2 = s_inp[kq * 4 + 2][b];
            const float a3 = s_inp[kq * 4 + 3][b];
            #pragma unroll
            for (int q = 0; q < 4; ++q) {
                const float4 w = *reinterpret_cast<const float4*>(&s_w[jg * 4 + q][kq * 4]);
                acc[q] = fmaf(w.x, a0, fmaf(w.y, a1, fmaf(w.z, a2, fmaf(w.w, a3, acc[q]))));
            }
        }
    }

    float* preK = kc ? pre1 : pre0;
    float4 r;
    r.x = acc[0]; r.y = acc[1]; r.z = acc[2]; r.w = acc[3];
    *reinterpret_cast<float4*>(preK + (size_t)b * HIDDEN + j0 + jg * 4) = r;
}

// ---------------------------------------------------------------------------
// Kernel C: 64 sequential RNN steps.
//   h_b = tanh(pre0[b]+pre1[b] + W_hh h_{b-1} + b_hh + b_ih)
// Grid: 768 blocks x 256 thr (3 blocks/CU, co-resident). 3072 waves; wave gw
// owns rows {gw, gw+3072} fused (shared h loads) and gw<480 also row gw+6144.
// h_{b-1} read from global (same addresses on all waves -> L1-hot).
// Two-level tree barrier: 64 padded leaf counters (12 arrivals each), block 0
// wave 0 polls all leaves with one 64-lane atomic load, publishes epoch.
// ---------------------------------------------------------------------------
__global__ __launch_bounds__(256, 3) void rnn_kernel(
    const float* __restrict__ Whh,      // (6624,6624)
    const float* __restrict__ b_hh,
    const float* __restrict__ b_ih,
    const float* __restrict__ pre0,     // (64,6624)
    const float* __restrict__ pre1,     // (64,6624)
    float* __restrict__ hz,             // (64,6624) output (also h chain)
    unsigned int* __restrict__ barrier_mem,  // leaves at +16*i words, epoch at +1024
    int bar_base)
{
    const int lane = threadIdx.x & 63;
    const int widx = threadIdx.x >> 6;
    const int gw = blockIdx.x * 4 + widx;      // 0..3071

    const int j1 = gw;
    const int j2 = gw + 3072;
    const int j3 = gw + 6144;                  // valid iff gw < 480

    const float4* W4 = reinterpret_cast<const float4*>(Whh);
    const float4* Wr1 = W4 + (size_t)j1 * H4;
    const float4* Wr2 = W4 + (size_t)j2 * H4;
    const float4* Wr3 = W4 + (size_t)j3 * H4;

    for (int b = 0; b < 64; ++b) {
        float s1 = 0.f, s2 = 0.f, s3 = 0.f;
        if (b > 0) {
            const float4* h4 = reinterpret_cast<const float4*>(hz + (size_t)(b - 1) * HIDDEN);
            float a1x = 0.f, a1y = 0.f, a1z = 0.f, a1w = 0.f;
            float a2x = 0.f, a2y = 0.f, a2z = 0.f, a2w = 0.f;
            #pragma unroll 8
            for (int it = 0; it < 25; ++it) {
                const float4 h = h4[it * 64 + lane];
                const float4 w1 = Wr1[it * 64 + lane];
                const float4 w2 = Wr2[it * 64 + lane];
                a1x = fmaf(w1.x, h.x, a1x); a1y = fmaf(w1.y, h.y, a1y);
                a1z = fmaf(w1.z, h.z, a1z); a1w = fmaf(w1.w, h.w, a1w);
                a2x = fmaf(w2.x, h.x, a2x); a2y = fmaf(w2.y, h.y, a2y);
                a2z = fmaf(w2.z, h.z, a2z); a2w = fmaf(w2.w, h.w, a2w);
            }
            if (lane < 56) {                   // tail: 1656 = 25*64 + 56
                const float4 h = h4[1600 + lane];
                const float4 w1 = Wr1[1600 + lane];
                const float4 w2 = Wr2[1600 + lane];
                a1x = fmaf(w1.x, h.x, a1x); a1y = fmaf(w1.y, h.y, a1y);
                a1z = fmaf(w1.z, h.z, a1z); a1w = fmaf(w1.w, h.w, a1w);
                a2x = fmaf(w2.x, h.x, a2x); a2y = fmaf(w2.y, h.y, a2y);
                a2z = fmaf(w2.z, h.z, a2z); a2w = fmaf(w2.w, h.w, a2w);
            }
            s1 = (a1x + a1y) + (a1z + a1w);
            s2 = (a2x + a2y) + (a2z + a2w);
            if (gw < 480) {
                float cx = 0.f, cy = 0.f, cz = 0.f, cw = 0.f;
                #pragma unroll 8
                for (int it = 0; it < 25; ++it) {
                    const float4 h = h4[it * 64 + lane];
                    const float4 w3 = Wr3[it * 64 + lane];
                    cx = fmaf(w3.x, h.x, cx); cy = fmaf(w3.y, h.y, cy);
                    cz = fmaf(w3.z, h.z, cz); cw = fmaf(w3.w, h.w, cw);
                }
                if (lane < 56) {
                    const float4 h = h4[1600 + lane];
                    const float4 w3 = Wr3[1600 + lane];
                    cx = fmaf(w3.x, h.x, cx); cy = fmaf(w3.y, h.y, cy);
                    cz = fmaf(w3.z, h.z, cz); cw = fmaf(w3.w, h.w, cw);
                }
                s3 = (cx + cy) + (cz + cw);
            }
        }
        #pragma unroll
        for (int off = 32; off > 0; off >>= 1) {
            s1 += __shfl_xor(s1, off, 64);
            s2 += __shfl_xor(s2, off, 64);
            s3 += __shfl_xor(s3, off, 64);
        }
        if (lane == 0) {
            const size_t rb = (size_t)b * HIDDEN;
            hz[rb + j1] = tanhf(pre0[rb + j1] + pre1[rb + j1] + b_hh[j1] + b_ih[j1] + s1);
            hz[rb + j2] = tanhf(pre0[rb + j2] + pre1[rb + j2] + b_hh[j2] + b_ih[j2] + s2);
            if (gw < 480)
                hz[rb + j3] = tanhf(pre0[rb + j3] + pre1[rb + j3] + b_hh[j3] + b_ih[j3] + s3);
        }

        if (b != 63) {
            const int gstep = bar_base + b;
            __syncthreads();
            if (threadIdx.x == 0) {
                __threadfence();   // agent-scope release of this block's hz stores
                __hip_atomic_fetch_add(barrier_mem + (size_t)(blockIdx.x & 63) * 16, 1u,
                                       __ATOMIC_ACQ_REL, __HIP_MEMORY_SCOPE_AGENT);
            }
            if (blockIdx.x == 0 && threadIdx.x < 64) {
                const unsigned int ltarget = 12u * (unsigned int)(gstep + 1);
                while (__hip_atomic_load(barrier_mem + (size_t)threadIdx.x * 16,
                                         __ATOMIC_ACQUIRE, __HIP_MEMORY_SCOPE_AGENT) < ltarget) {
                    __builtin_amdgcn_s_sleep(1);
                }
                if (threadIdx.x == 0)
                    __hip_atomic_fetch_add(barrier_mem + 1024, 1u,
                                           __ATOMIC_ACQ_REL, __HIP_MEMORY_SCOPE_AGENT);
            }
            if (threadIdx.x == 0) {
                const unsigned int etarget = (unsigned int)(gstep + 1);
                while (__hip_atomic_load(barrier_mem + 1024,
                                         __ATOMIC_ACQUIRE, __HIP_MEMORY_SCOPE_AGENT) < etarget) {
                    __builtin_amdgcn_s_sleep(1);
                }
            }
            __syncthreads();
        }
    }
}

// ---------------------------------------------------------------------------
extern "C" void kernel_launch(void* const* d_in, const int* in_sizes, int n_in,
                              void* d_out, int out_size, void* d_ws, size_t ws_size,
                              hipStream_t stream)
{
    const float* spline = (const float*)d_in[0];   // (12,64,207,2)
    const float* init0  = (const float*)d_in[1];   // (64,6624)
    const float* Wf     = (const float*)d_in[2];   // (16,32)
    const float* bf     = (const float*)d_in[3];   // (32,)
    const float* Wg     = (const float*)d_in[4];   // (16,256)
    const float* bg     = (const float*)d_in[5];   // (256,)
    const float* conv_w = (const float*)d_in[6];   // (16,)
    const float* Wih    = (const float*)d_in[7];   // (6624,16560)
    const float* b_ih   = (const float*)d_in[8];   // (6624,)
    const float* Whh    = (const float*)d_in[9];   // (6624,6624)
    const float* b_hh   = (const float*)d_in[10];  // (6624,)
    float* out = (float*)d_out;

    char* ws = (char*)d_ws;
    unsigned int* bar = (unsigned int*)ws;                       // 8192 B region
    float* inpT = (float*)(ws + 8192);                           // 4,239,360 B
    float* pre0 = (float*)(ws + 8192 + 4239360);                 // 1,695,744 B
    float* pre1 = (float*)(ws + 8192 + 4239360 + 1695744);       // 1,695,744 B
    float* hz_ws = (float*)(ws + 8192 + 4239360 + 2 * 1695744);  // 1,695,744 B

    hipMemsetAsync(bar, 0, 8192, stream);

    for (int t = 0; t < TSTEPS; ++t) {
        const float* hz_in = (t == 0) ? init0 : hz_ws;
        float* hz_out = (t == TSTEPS - 1) ? out : hz_ws;

        build_inp_kernel<<<BATCH * NODE, 256, 0, stream>>>(
            spline, hz_in, Wf, bf, Wg, bg, conv_w, inpT, t);

        gemm_ih_kernel<<<828, 256, 0, stream>>>(Wih, inpT, pre0, pre1);

        rnn_kernel<<<768, 256, 0, stream>>>(
            Whh, b_hh, b_ih, pre0, pre1, hz_out, bar, t * 63);
    }
}